// Round 7
// baseline (24.251 us; speedup 1.0000x reference)
//
#include <hip/hip_runtime.h>

#define NBINS 256
#define BPS   32     // blocks per sample -> 128*32 = 4096 blocks
#define NT    256    // threads per block (4 waves)
#define NWAVE (NT / 64)

typedef float floatx4 __attribute__((ext_vector_type(4)));  // native vec for nt-load

// ---------------- Kernel 1: per-block partial histograms ----------------
// Compile-time trip count; all loads issued up front (nontemporal); 8 waves/SIMD
// occupancy floor so 8 blocks/CU keep reads in flight while DS atomics drain.
template<int N4>   // float4 elements per block (compile-time)
__global__ __launch_bounds__(NT, 8) void hist_kernel_t(const float* __restrict__ x,
                                                       unsigned int* __restrict__ phist,
                                                       float* __restrict__ out) {
    __shared__ unsigned int lh[NWAVE][NBINS];
    const int tid  = threadIdx.x;
    const int wave = tid >> 6;

    if (blockIdx.x == 0 && tid == 0) out[0] = 0.0f;

    for (int i = tid; i < NWAVE * NBINS; i += NT)
        ((unsigned int*)lh)[i] = 0u;

    constexpr int ITER = N4 / NT;                    // 6 for N=196608, BPS=32
    const floatx4* src = (const floatx4*)x + (size_t)blockIdx.x * N4;

    // issue ALL loads first (independent, streaming/nontemporal)
    floatx4 v[ITER];
    #pragma unroll
    for (int i = 0; i < ITER; ++i)
        v[i] = __builtin_nontemporal_load(&src[tid + i * NT]);

    __syncthreads();   // lh zeroing complete (loads already in flight)

    #pragma unroll
    for (int i = 0; i < ITER; ++i) {
        // clamp on float side: min(v*256, 255); cvt-to-unsigned saturates
        // negatives to 0 -> identical to (int)(v*256) clipped to [0,255].
        unsigned int i0 = (unsigned int)fminf(v[i].x * 256.0f, 255.0f);
        unsigned int i1 = (unsigned int)fminf(v[i].y * 256.0f, 255.0f);
        unsigned int i2 = (unsigned int)fminf(v[i].z * 256.0f, 255.0f);
        unsigned int i3 = (unsigned int)fminf(v[i].w * 256.0f, 255.0f);
        atomicAdd(&lh[wave][i0], 1u);
        atomicAdd(&lh[wave][i1], 1u);
        atomicAdd(&lh[wave][i2], 1u);
        atomicAdd(&lh[wave][i3], 1u);
    }
    __syncthreads();

    unsigned int* dst = phist + (size_t)blockIdx.x * NBINS;
    for (int bin = tid; bin < NBINS; bin += NT) {
        unsigned int s = 0;
        #pragma unroll
        for (int w = 0; w < NWAVE; ++w) s += lh[w][bin];
        dst[bin] = s;
    }
}

// Generic fallback (runtime sizes) — same math, loop version.
__global__ __launch_bounds__(NT) void hist_kernel_g(const float* __restrict__ x,
                                                    unsigned int* __restrict__ phist,
                                                    float* __restrict__ out,
                                                    int n_per_sample) {
    __shared__ unsigned int lh[NWAVE][NBINS];
    const int tid  = threadIdx.x;
    const int wave = tid >> 6;
    if (blockIdx.x == 0 && tid == 0) out[0] = 0.0f;
    for (int i = tid; i < NWAVE * NBINS; i += NT)
        ((unsigned int*)lh)[i] = 0u;
    __syncthreads();
    const int b     = blockIdx.x / BPS;
    const int blk   = blockIdx.x % BPS;
    const int chunk = n_per_sample / BPS;
    const float4* src = (const float4*)(x + (size_t)b * n_per_sample
                                          + (size_t)blk * chunk);
    const int n4 = chunk >> 2;
    for (int i = tid; i < n4; i += NT) {
        float4 v = src[i];
        unsigned int i0 = (unsigned int)fminf(v.x * 256.0f, 255.0f);
        unsigned int i1 = (unsigned int)fminf(v.y * 256.0f, 255.0f);
        unsigned int i2 = (unsigned int)fminf(v.z * 256.0f, 255.0f);
        unsigned int i3 = (unsigned int)fminf(v.w * 256.0f, 255.0f);
        atomicAdd(&lh[wave][i0], 1u);
        atomicAdd(&lh[wave][i1], 1u);
        atomicAdd(&lh[wave][i2], 1u);
        atomicAdd(&lh[wave][i3], 1u);
    }
    __syncthreads();
    unsigned int* dst = phist + (size_t)blockIdx.x * NBINS;
    for (int bin = tid; bin < NBINS; bin += NT) {
        unsigned int s = 0;
        #pragma unroll
        for (int w = 0; w < NWAVE; ++w) s += lh[w][bin];
        dst[bin] = s;
    }
}

// ---------------- Kernel 2: sum partials -> entropy -> MSE contribution ----------------
__global__ __launch_bounds__(NBINS) void entropy_kernel(const unsigned int* __restrict__ phist,
                                                        const float* __restrict__ target,
                                                        float* __restrict__ out,
                                                        float inv_n, float inv_b) {
    const int b   = blockIdx.x;
    const int tid = threadIdx.x;

    const unsigned int* base = phist + (size_t)b * BPS * NBINS;
    unsigned int h = 0;
    #pragma unroll
    for (int k = 0; k < BPS; ++k) h += base[k * NBINS + tid];

    float t = 0.0f;
    if (h > 0u) {
        float p = (float)h * inv_n;
        t = -p * log2f(p);
    }
    #pragma unroll
    for (int off = 32; off > 0; off >>= 1) t += __shfl_down(t, off, 64);
    __shared__ float ws[NBINS / 64];
    if ((tid & 63) == 0) ws[tid >> 6] = t;
    __syncthreads();
    if (tid == 0) {
        float ent = 0.0f;
        #pragma unroll
        for (int w = 0; w < NBINS / 64; ++w) ent += ws[w];
        float d = ent - target[b];
        atomicAdd(out, d * d * inv_b);
    }
}

extern "C" void kernel_launch(void* const* d_in, const int* in_sizes, int n_in,
                              void* d_out, int out_size, void* d_ws, size_t ws_size,
                              hipStream_t stream) {
    const float* x      = (const float*)d_in[0];
    const float* target = (const float*)d_in[1];
    float* out          = (float*)d_out;

    const int B = in_sizes[1];                 // 128
    const int N = in_sizes[0] / B;             // 196608

    unsigned int* phist = (unsigned int*)d_ws; // B*BPS*NBINS uints (4 MB)

    if (N == 196608) {
        constexpr int N4 = (196608 / BPS) / 4; // 1536 float4 per block
        hist_kernel_t<N4><<<B * BPS, NT, 0, stream>>>(x, phist, out);
    } else {
        hist_kernel_g<<<B * BPS, NT, 0, stream>>>(x, phist, out, N);
    }
    entropy_kernel<<<B, NBINS, 0, stream>>>(phist, target, out,
                                            1.0f / (float)N, 1.0f / (float)B);
}

// Round 8
// 23.796 us; speedup vs baseline: 1.0191x; 1.0191x over previous
//
#include <hip/hip_runtime.h>

#define NBINS 256
#define BPS   8      // blocks per sample -> 128*8 = 1024 blocks (4/CU, 16 waves/CU)
#define NT    256    // threads per block (4 waves)
#define NWAVE (NT / 64)

typedef float floatx4 __attribute__((ext_vector_type(4)));  // native vec for nt-load

// ---------------- Kernel 1: per-block partial histograms ----------------
// Deep per-wave pipeline: all 24 float4 loads issued up front; LDS atomics
// proceed in quarters under staged vmcnt waits, so DS work overlaps the
// still-in-flight loads instead of serializing VMEM-phase -> DS-phase.
template<int N4>   // float4 elements per block (compile-time; 6144 here)
__global__ __launch_bounds__(NT, 4) void hist_kernel_t(const float* __restrict__ x,
                                                       unsigned int* __restrict__ phist,
                                                       float* __restrict__ out) {
    __shared__ unsigned int lh[NWAVE][NBINS];
    const int tid  = threadIdx.x;
    const int wave = tid >> 6;

    if (blockIdx.x == 0 && tid == 0) out[0] = 0.0f;

    for (int i = tid; i < NWAVE * NBINS; i += NT)
        ((unsigned int*)lh)[i] = 0u;

    constexpr int ITER = N4 / NT;                    // 24
    const floatx4* src = (const floatx4*)x + (size_t)blockIdx.x * N4;

    // issue ALL loads first (independent, streaming/nontemporal)
    floatx4 v[ITER];
    #pragma unroll
    for (int i = 0; i < ITER; ++i)
        v[i] = __builtin_nontemporal_load(&src[tid + i * NT]);

    __syncthreads();   // lh zeroing complete (loads already in flight)

    // atomics in order v[0..23]: compiler stages s_waitcnt vmcnt(N) so the
    // DS pipe works on early quarters while later loads are still in flight.
    #pragma unroll
    for (int i = 0; i < ITER; ++i) {
        unsigned int i0 = (unsigned int)fminf(v[i].x * 256.0f, 255.0f);
        unsigned int i1 = (unsigned int)fminf(v[i].y * 256.0f, 255.0f);
        unsigned int i2 = (unsigned int)fminf(v[i].z * 256.0f, 255.0f);
        unsigned int i3 = (unsigned int)fminf(v[i].w * 256.0f, 255.0f);
        atomicAdd(&lh[wave][i0], 1u);
        atomicAdd(&lh[wave][i1], 1u);
        atomicAdd(&lh[wave][i2], 1u);
        atomicAdd(&lh[wave][i3], 1u);
    }
    __syncthreads();

    // merge waves: 256 threads, 256 bins -> one bin per thread
    unsigned int* dst = phist + (size_t)blockIdx.x * NBINS;
    unsigned int s = 0;
    #pragma unroll
    for (int w = 0; w < NWAVE; ++w) s += lh[w][tid];
    dst[tid] = s;
}

// Generic fallback (runtime sizes) — same math, loop version.
__global__ __launch_bounds__(NT) void hist_kernel_g(const float* __restrict__ x,
                                                    unsigned int* __restrict__ phist,
                                                    float* __restrict__ out,
                                                    int n_per_sample) {
    __shared__ unsigned int lh[NWAVE][NBINS];
    const int tid  = threadIdx.x;
    const int wave = tid >> 6;
    if (blockIdx.x == 0 && tid == 0) out[0] = 0.0f;
    for (int i = tid; i < NWAVE * NBINS; i += NT)
        ((unsigned int*)lh)[i] = 0u;
    __syncthreads();
    const int b     = blockIdx.x / BPS;
    const int blk   = blockIdx.x % BPS;
    const int chunk = n_per_sample / BPS;
    const float4* src = (const float4*)(x + (size_t)b * n_per_sample
                                          + (size_t)blk * chunk);
    const int n4 = chunk >> 2;
    for (int i = tid; i < n4; i += NT) {
        float4 v = src[i];
        unsigned int i0 = (unsigned int)fminf(v.x * 256.0f, 255.0f);
        unsigned int i1 = (unsigned int)fminf(v.y * 256.0f, 255.0f);
        unsigned int i2 = (unsigned int)fminf(v.z * 256.0f, 255.0f);
        unsigned int i3 = (unsigned int)fminf(v.w * 256.0f, 255.0f);
        atomicAdd(&lh[wave][i0], 1u);
        atomicAdd(&lh[wave][i1], 1u);
        atomicAdd(&lh[wave][i2], 1u);
        atomicAdd(&lh[wave][i3], 1u);
    }
    __syncthreads();
    unsigned int* dst = phist + (size_t)blockIdx.x * NBINS;
    for (int bin = tid; bin < NBINS; bin += NT) {
        unsigned int s = 0;
        #pragma unroll
        for (int w = 0; w < NWAVE; ++w) s += lh[w][bin];
        dst[bin] = s;
    }
}

// ---------------- Kernel 2: sum partials -> entropy -> MSE contribution ----------------
__global__ __launch_bounds__(NBINS) void entropy_kernel(const unsigned int* __restrict__ phist,
                                                        const float* __restrict__ target,
                                                        float* __restrict__ out,
                                                        float inv_n, float inv_b) {
    const int b   = blockIdx.x;
    const int tid = threadIdx.x;

    const unsigned int* base = phist + (size_t)b * BPS * NBINS;
    unsigned int h = 0;
    #pragma unroll
    for (int k = 0; k < BPS; ++k) h += base[k * NBINS + tid];

    float t = 0.0f;
    if (h > 0u) {
        float p = (float)h * inv_n;
        t = -p * log2f(p);
    }
    #pragma unroll
    for (int off = 32; off > 0; off >>= 1) t += __shfl_down(t, off, 64);
    __shared__ float ws[NBINS / 64];
    if ((tid & 63) == 0) ws[tid >> 6] = t;
    __syncthreads();
    if (tid == 0) {
        float ent = 0.0f;
        #pragma unroll
        for (int w = 0; w < NBINS / 64; ++w) ent += ws[w];
        float d = ent - target[b];
        atomicAdd(out, d * d * inv_b);
    }
}

extern "C" void kernel_launch(void* const* d_in, const int* in_sizes, int n_in,
                              void* d_out, int out_size, void* d_ws, size_t ws_size,
                              hipStream_t stream) {
    const float* x      = (const float*)d_in[0];
    const float* target = (const float*)d_in[1];
    float* out          = (float*)d_out;

    const int B = in_sizes[1];                 // 128
    const int N = in_sizes[0] / B;             // 196608

    unsigned int* phist = (unsigned int*)d_ws; // B*BPS*NBINS uints (1 MB)

    if (N == 196608) {
        constexpr int N4 = (196608 / BPS) / 4; // 6144 float4 per block
        hist_kernel_t<N4><<<B * BPS, NT, 0, stream>>>(x, phist, out);
    } else {
        hist_kernel_g<<<B * BPS, NT, 0, stream>>>(x, phist, out, N);
    }
    entropy_kernel<<<B, NBINS, 0, stream>>>(phist, target, out,
                                            1.0f / (float)N, 1.0f / (float)B);
}

// Round 9
// 23.532 us; speedup vs baseline: 1.0305x; 1.0112x over previous
//
#include <hip/hip_runtime.h>

#define NBINS 256
#define BPS   8      // blocks per sample -> 128*8 = 1024 blocks (4/CU)
#define NT    256    // threads per block (4 waves)
#define NCOPY 32     // histogram copies; copy c lives entirely in LDS bank c

typedef float floatx4 __attribute__((ext_vector_type(4)));  // native vec for nt-load

// ---------------- Kernel 1: per-block partial histograms ----------------
// Bank-conflict-free: histogram replicated 32x, word(b,c) = b*32 + c so copy c
// maps to bank c only. Lane l updates copy l&31 -> bank = lane&31 always,
// independent of the data. All loads issued up front (nontemporal).
template<int N4>   // float4 elements per block (compile-time; 6144 here)
__global__ __launch_bounds__(NT, 4) void hist_kernel_t(const float* __restrict__ x,
                                                       unsigned int* __restrict__ phist,
                                                       float* __restrict__ out) {
    __shared__ unsigned int lh[NBINS * NCOPY];   // 32 KB
    const int tid  = threadIdx.x;
    const int lane = tid & 31;                   // copy / bank id

    if (blockIdx.x == 0 && tid == 0) out[0] = 0.0f;

    // zero 8192 words: addr = k*256 + tid -> bank tid%32, conflict-free
    #pragma unroll
    for (int k = 0; k < NBINS * NCOPY / NT; ++k)
        lh[k * NT + tid] = 0u;

    constexpr int ITER = N4 / NT;                // 24
    const floatx4* src = (const floatx4*)x + (size_t)blockIdx.x * N4;

    floatx4 v[ITER];
    #pragma unroll
    for (int i = 0; i < ITER; ++i)
        v[i] = __builtin_nontemporal_load(&src[tid + i * NT]);

    __syncthreads();   // zeroing complete (loads already in flight)

    #pragma unroll
    for (int i = 0; i < ITER; ++i) {
        unsigned int i0 = (unsigned int)fminf(v[i].x * 256.0f, 255.0f);
        unsigned int i1 = (unsigned int)fminf(v[i].y * 256.0f, 255.0f);
        unsigned int i2 = (unsigned int)fminf(v[i].z * 256.0f, 255.0f);
        unsigned int i3 = (unsigned int)fminf(v[i].w * 256.0f, 255.0f);
        atomicAdd(&lh[(i0 << 5) | lane], 1u);
        atomicAdd(&lh[(i1 << 5) | lane], 1u);
        atomicAdd(&lh[(i2 << 5) | lane], 1u);
        atomicAdd(&lh[(i3 << 5) | lane], 1u);
    }
    __syncthreads();

    // merge: thread t owns bin t; rotate copy order (t+k)&31 so step k's
    // banks are all distinct across lanes -> conflict-free
    unsigned int s = 0;
    #pragma unroll
    for (int k = 0; k < NCOPY; ++k)
        s += lh[(tid << 5) | ((tid + k) & 31)];
    phist[(size_t)blockIdx.x * NBINS + tid] = s;
}

// Generic fallback (runtime sizes) — simple loop version.
__global__ __launch_bounds__(NT) void hist_kernel_g(const float* __restrict__ x,
                                                    unsigned int* __restrict__ phist,
                                                    float* __restrict__ out,
                                                    int n_per_sample) {
    __shared__ unsigned int lh[NBINS * NCOPY];
    const int tid  = threadIdx.x;
    const int lane = tid & 31;
    if (blockIdx.x == 0 && tid == 0) out[0] = 0.0f;
    for (int k = 0; k < NBINS * NCOPY / NT; ++k)
        lh[k * NT + tid] = 0u;
    __syncthreads();
    const int b     = blockIdx.x / BPS;
    const int blk   = blockIdx.x % BPS;
    const int chunk = n_per_sample / BPS;
    const float4* src = (const float4*)(x + (size_t)b * n_per_sample
                                          + (size_t)blk * chunk);
    const int n4 = chunk >> 2;
    for (int i = tid; i < n4; i += NT) {
        float4 v = src[i];
        unsigned int i0 = (unsigned int)fminf(v.x * 256.0f, 255.0f);
        unsigned int i1 = (unsigned int)fminf(v.y * 256.0f, 255.0f);
        unsigned int i2 = (unsigned int)fminf(v.z * 256.0f, 255.0f);
        unsigned int i3 = (unsigned int)fminf(v.w * 256.0f, 255.0f);
        atomicAdd(&lh[(i0 << 5) | lane], 1u);
        atomicAdd(&lh[(i1 << 5) | lane], 1u);
        atomicAdd(&lh[(i2 << 5) | lane], 1u);
        atomicAdd(&lh[(i3 << 5) | lane], 1u);
    }
    __syncthreads();
    unsigned int s = 0;
    #pragma unroll
    for (int k = 0; k < NCOPY; ++k)
        s += lh[(tid << 5) | ((tid + k) & 31)];
    phist[(size_t)blockIdx.x * NBINS + tid] = s;
}

// ---------------- Kernel 2: sum partials -> entropy -> MSE contribution ----------------
__global__ __launch_bounds__(NBINS) void entropy_kernel(const unsigned int* __restrict__ phist,
                                                        const float* __restrict__ target,
                                                        float* __restrict__ out,
                                                        float inv_n, float inv_b) {
    const int b   = blockIdx.x;
    const int tid = threadIdx.x;

    const unsigned int* base = phist + (size_t)b * BPS * NBINS;
    unsigned int h = 0;
    #pragma unroll
    for (int k = 0; k < BPS; ++k) h += base[k * NBINS + tid];

    float t = 0.0f;
    if (h > 0u) {
        float p = (float)h * inv_n;
        t = -p * log2f(p);
    }
    #pragma unroll
    for (int off = 32; off > 0; off >>= 1) t += __shfl_down(t, off, 64);
    __shared__ float ws[NBINS / 64];
    if ((tid & 63) == 0) ws[tid >> 6] = t;
    __syncthreads();
    if (tid == 0) {
        float ent = 0.0f;
        #pragma unroll
        for (int w = 0; w < NBINS / 64; ++w) ent += ws[w];
        float d = ent - target[b];
        atomicAdd(out, d * d * inv_b);
    }
}

extern "C" void kernel_launch(void* const* d_in, const int* in_sizes, int n_in,
                              void* d_out, int out_size, void* d_ws, size_t ws_size,
                              hipStream_t stream) {
    const float* x      = (const float*)d_in[0];
    const float* target = (const float*)d_in[1];
    float* out          = (float*)d_out;

    const int B = in_sizes[1];                 // 128
    const int N = in_sizes[0] / B;             // 196608

    unsigned int* phist = (unsigned int*)d_ws; // B*BPS*NBINS uints (1 MB)

    if (N == 196608) {
        constexpr int N4 = (196608 / BPS) / 4; // 6144 float4 per block
        hist_kernel_t<N4><<<B * BPS, NT, 0, stream>>>(x, phist, out);
    } else {
        hist_kernel_g<<<B * BPS, NT, 0, stream>>>(x, phist, out, N);
    }
    entropy_kernel<<<B, NBINS, 0, stream>>>(phist, target, out,
                                            1.0f / (float)N, 1.0f / (float)B);
}

// Round 10
// 22.894 us; speedup vs baseline: 1.0593x; 1.0279x over previous
//
#include <hip/hip_runtime.h>

#define NBINS 256
#define BPS   16     // blocks per sample -> 128*16 = 2048 blocks (16/CU total, 8 resident -> 2 generations)
#define NT    256    // threads per block (4 waves)
#define NCOPY 16     // histogram copies; 16 KB LDS -> 8 blocks/CU resident

typedef float floatx4 __attribute__((ext_vector_type(4)));  // native vec for nt-load

// ---------------- Kernel 1: per-block partial histograms ----------------
// Conflict-free(ish) replicated histogram: word(bin,c) = bin*16 + c, c = lane&15.
// Bank = c + 16*(bin&1): lanes sharing c are 4 apart -> typically 2-way (free).
// 16 KB LDS x 8 resident blocks/CU = 128 KB; second generation of blocks
// issues its loads while the first drains DS/merge/store (tail hiding).
template<int N4>   // float4 elements per block (compile-time; 3072 here)
__global__ __launch_bounds__(NT, 8) void hist_kernel_t(const float* __restrict__ x,
                                                       unsigned int* __restrict__ phist,
                                                       float* __restrict__ out) {
    __shared__ unsigned int lh[NBINS * NCOPY];   // 16 KB
    const int tid  = threadIdx.x;
    const int copy = tid & (NCOPY - 1);

    if (blockIdx.x == 0 && tid == 0) out[0] = 0.0f;

    #pragma unroll
    for (int k = 0; k < NBINS * NCOPY / NT; ++k)
        lh[k * NT + tid] = 0u;

    constexpr int ITER = N4 / NT;                // 12
    const floatx4* src = (const floatx4*)x + (size_t)blockIdx.x * N4;

    floatx4 v[ITER];
    #pragma unroll
    for (int i = 0; i < ITER; ++i)
        v[i] = __builtin_nontemporal_load(&src[tid + i * NT]);

    __syncthreads();   // zeroing complete (loads already in flight)

    #pragma unroll
    for (int i = 0; i < ITER; ++i) {
        unsigned int i0 = (unsigned int)fminf(v[i].x * 256.0f, 255.0f);
        unsigned int i1 = (unsigned int)fminf(v[i].y * 256.0f, 255.0f);
        unsigned int i2 = (unsigned int)fminf(v[i].z * 256.0f, 255.0f);
        unsigned int i3 = (unsigned int)fminf(v[i].w * 256.0f, 255.0f);
        atomicAdd(&lh[(i0 << 4) | copy], 1u);
        atomicAdd(&lh[(i1 << 4) | copy], 1u);
        atomicAdd(&lh[(i2 << 4) | copy], 1u);
        atomicAdd(&lh[(i3 << 4) | copy], 1u);
    }
    __syncthreads();

    // merge: thread t owns bin t; rotate copy order to spread banks
    unsigned int s = 0;
    #pragma unroll
    for (int k = 0; k < NCOPY; ++k)
        s += lh[(tid << 4) | ((tid + k) & (NCOPY - 1))];
    phist[(size_t)blockIdx.x * NBINS + tid] = s;
}

// Generic fallback (runtime sizes) — simple loop version.
__global__ __launch_bounds__(NT) void hist_kernel_g(const float* __restrict__ x,
                                                    unsigned int* __restrict__ phist,
                                                    float* __restrict__ out,
                                                    int n_per_sample) {
    __shared__ unsigned int lh[NBINS * NCOPY];
    const int tid  = threadIdx.x;
    const int copy = tid & (NCOPY - 1);
    if (blockIdx.x == 0 && tid == 0) out[0] = 0.0f;
    for (int k = 0; k < NBINS * NCOPY / NT; ++k)
        lh[k * NT + tid] = 0u;
    __syncthreads();
    const int b     = blockIdx.x / BPS;
    const int blk   = blockIdx.x % BPS;
    const int chunk = n_per_sample / BPS;
    const float4* src = (const float4*)(x + (size_t)b * n_per_sample
                                          + (size_t)blk * chunk);
    const int n4 = chunk >> 2;
    for (int i = tid; i < n4; i += NT) {
        float4 v = src[i];
        unsigned int i0 = (unsigned int)fminf(v.x * 256.0f, 255.0f);
        unsigned int i1 = (unsigned int)fminf(v.y * 256.0f, 255.0f);
        unsigned int i2 = (unsigned int)fminf(v.z * 256.0f, 255.0f);
        unsigned int i3 = (unsigned int)fminf(v.w * 256.0f, 255.0f);
        atomicAdd(&lh[(i0 << 4) | copy], 1u);
        atomicAdd(&lh[(i1 << 4) | copy], 1u);
        atomicAdd(&lh[(i2 << 4) | copy], 1u);
        atomicAdd(&lh[(i3 << 4) | copy], 1u);
    }
    __syncthreads();
    unsigned int s = 0;
    #pragma unroll
    for (int k = 0; k < NCOPY; ++k)
        s += lh[(tid << 4) | ((tid + k) & (NCOPY - 1))];
    phist[(size_t)blockIdx.x * NBINS + tid] = s;
}

// ---------------- Kernel 2: sum partials -> entropy -> MSE contribution ----------------
__global__ __launch_bounds__(NBINS) void entropy_kernel(const unsigned int* __restrict__ phist,
                                                        const float* __restrict__ target,
                                                        float* __restrict__ out,
                                                        float inv_n, float inv_b) {
    const int b   = blockIdx.x;
    const int tid = threadIdx.x;

    const unsigned int* base = phist + (size_t)b * BPS * NBINS;
    unsigned int h = 0;
    #pragma unroll
    for (int k = 0; k < BPS; ++k) h += base[k * NBINS + tid];

    float t = 0.0f;
    if (h > 0u) {
        float p = (float)h * inv_n;
        t = -p * log2f(p);
    }
    #pragma unroll
    for (int off = 32; off > 0; off >>= 1) t += __shfl_down(t, off, 64);
    __shared__ float ws[NBINS / 64];
    if ((tid & 63) == 0) ws[tid >> 6] = t;
    __syncthreads();
    if (tid == 0) {
        float ent = 0.0f;
        #pragma unroll
        for (int w = 0; w < NBINS / 64; ++w) ent += ws[w];
        float d = ent - target[b];
        atomicAdd(out, d * d * inv_b);
    }
}

extern "C" void kernel_launch(void* const* d_in, const int* in_sizes, int n_in,
                              void* d_out, int out_size, void* d_ws, size_t ws_size,
                              hipStream_t stream) {
    const float* x      = (const float*)d_in[0];
    const float* target = (const float*)d_in[1];
    float* out          = (float*)d_out;

    const int B = in_sizes[1];                 // 128
    const int N = in_sizes[0] / B;             // 196608

    unsigned int* phist = (unsigned int*)d_ws; // B*BPS*NBINS uints (2 MB)

    if (N == 196608) {
        constexpr int N4 = (196608 / BPS) / 4; // 3072 float4 per block
        hist_kernel_t<N4><<<B * BPS, NT, 0, stream>>>(x, phist, out);
    } else {
        hist_kernel_g<<<B * BPS, NT, 0, stream>>>(x, phist, out, N);
    }
    entropy_kernel<<<B, NBINS, 0, stream>>>(phist, target, out,
                                            1.0f / (float)N, 1.0f / (float)B);
}